// Round 8
// baseline (411.594 us; speedup 1.0000x reference)
//
#include <hip/hip_runtime.h>

typedef _Float16 h8  __attribute__((ext_vector_type(8)));
typedef float f32x16 __attribute__((ext_vector_type(16)));

#define L2E 1.4426950408889634f

__device__ __forceinline__ void gll16(const void* g, void* l) {
  __builtin_amdgcn_global_load_lds((const __attribute__((address_space(1))) void*)g,
                                   (__attribute__((address_space(3))) void*)l, 16, 0, 0);
}

// ---------------- kernel 0: x (f32) -> xh (f16) ----------------
__global__ void k_cvt_x(const float* __restrict__ x, _Float16* __restrict__ xh) {
  int i = (blockIdx.x * 256 + threadIdx.x) * 8;
  float4 a = *(const float4*)(x + i);
  float4 b = *(const float4*)(x + i + 4);
  h8 o;
  o[0] = (_Float16)a.x; o[1] = (_Float16)a.y; o[2] = (_Float16)a.z; o[3] = (_Float16)a.w;
  o[4] = (_Float16)b.x; o[5] = (_Float16)b.y; o[6] = (_Float16)b.z; o[7] = (_Float16)b.w;
  *(h8*)(xh + i) = o;
}

// ---------------- kernel 0b: W (1024x128 f32) -> WT (3x128x1024 f16) ------
__global__ void k_cvt_w(const float* __restrict__ Wq, const float* __restrict__ Wk,
                        const float* __restrict__ Wv, _Float16* __restrict__ WT) {
  int id = blockIdx.x * 256 + threadIdx.x;     // 0 .. 3*131072-1
  int mat = id >> 17;
  int rem = id & 131071;
  int k = rem >> 7;
  int c = rem & 127;
  const float* W = (mat == 0) ? Wq : ((mat == 1) ? Wk : Wv);
  WT[mat * 131072 + c * 1024 + k] = (_Float16)W[rem];
}

// ---------------- kernel 1: QKV projection + rotary + gate ----------------
// grid = 128 row-tiles * 3 matrices; 256 threads (4 waves of 2x2 over 128x128)
// Q: row-major [16384][128].
// K: fragment-major for mfma_32x32x16 A-operand:
//    half-index = (kv>>5)*4096 + (d>>4)*512 + ((d>>3)&1)*256 + (kv&31)*8 + (d&7)
// V: fragment-major (A-operand of PV, rows = d, k-dim = kv):
//    half-index = (kv>>5)*4096 + ((d>>5)*2 + ((kv>>4)&1))*512 + ((kv>>3)&1)*256 + (d&31)*8 + (kv&7)
__global__ __launch_bounds__(256, 2) void k_proj(
    const _Float16* __restrict__ xh,   // [16384][1024]
    const _Float16* __restrict__ WT,   // [3][128][1024]
    const float* __restrict__ cosT, const float* __restrict__ sinT,  // [4096][64]
    const float* __restrict__ gamma,
    _Float16* __restrict__ Qh, _Float16* __restrict__ Kh, _Float16* __restrict__ VT) {
  __shared__ __align__(16) unsigned char lds[65536];  // [2 phase][x 16KB | w 16KB]
  const int tid = threadIdx.x;
  const int rt  = blockIdx.x & 127;
  const int mat = blockIdx.x >> 7;
  const int w = tid >> 6, lane = tid & 63;
  const int wr = w >> 1, wc = w & 1;
  const int r32 = lane & 31, h = lane >> 5;
  const int row0 = rt * 128;
  const _Float16* Wbase = WT + mat * 131072;

  auto stage = [&](int j) {
    int k0 = j * 64;
    unsigned char* xb = lds + (j & 1) * 32768;
    unsigned char* wb = xb + 16384;
#pragma unroll
    for (int ii = 0; ii < 4; ++ii) {
      int off = ii * 4096 + tid * 16;
      int r = off >> 7;            // row in tile (128B rows)
      int c = (off >> 4) & 7;      // 16B chunk slot
      gll16(xh + (size_t)(row0 + r) * 1024 + k0 + ((c ^ (r & 7)) * 8), xb + off);
    }
#pragma unroll
    for (int ii = 0; ii < 4; ++ii) {
      int off = ii * 4096 + tid * 16;
      int r = off >> 7;
      int c = (off >> 4) & 7;
      gll16(Wbase + (size_t)r * 1024 + k0 + ((c ^ (r & 7)) * 8), wb + off);
    }
  };

  f32x16 acc[2][2];
#pragma unroll
  for (int a_ = 0; a_ < 2; ++a_)
#pragma unroll
    for (int b_ = 0; b_ < 2; ++b_)
#pragma unroll
      for (int r = 0; r < 16; ++r) acc[a_][b_][r] = 0.f;

  stage(0);
  for (int j = 0; j < 16; ++j) {
    if (j < 15) {
      stage(j + 1);
      asm volatile("s_waitcnt vmcnt(8)\n\ts_barrier" ::: "memory");
    } else {
      asm volatile("s_waitcnt vmcnt(0)\n\ts_barrier" ::: "memory");
    }
    const _Float16* xt = (const _Float16*)(lds + (j & 1) * 32768);
    const _Float16* wt = xt + 8192;
#pragma unroll
    for (int kk = 0; kk < 4; ++kk) {
      h8 a0, a1, b0, b1;
      { int r = wr * 64 + r32;      a0 = *(const h8*)(xt + r * 64 + (((kk * 2 + h) ^ (r & 7)) * 8)); }
      { int r = wr * 64 + 32 + r32; a1 = *(const h8*)(xt + r * 64 + (((kk * 2 + h) ^ (r & 7)) * 8)); }
      { int r = wc * 64 + r32;      b0 = *(const h8*)(wt + r * 64 + (((kk * 2 + h) ^ (r & 7)) * 8)); }
      { int r = wc * 64 + 32 + r32; b1 = *(const h8*)(wt + r * 64 + (((kk * 2 + h) ^ (r & 7)) * 8)); }
      acc[0][0] = __builtin_amdgcn_mfma_f32_32x32x16_f16(a0, b0, acc[0][0], 0, 0, 0);
      acc[0][1] = __builtin_amdgcn_mfma_f32_32x32x16_f16(a0, b1, acc[0][1], 0, 0, 0);
      acc[1][0] = __builtin_amdgcn_mfma_f32_32x32x16_f16(a1, b0, acc[1][0], 0, 0, 0);
      acc[1][1] = __builtin_amdgcn_mfma_f32_32x32x16_f16(a1, b1, acc[1][1], 0, 0, 0);
    }
    asm volatile("s_waitcnt lgkmcnt(0)\n\ts_barrier" ::: "memory");
  }

#pragma unroll
  for (int mt = 0; mt < 2; ++mt)
#pragma unroll
    for (int nt = 0; nt < 2; ++nt) {
      int col = wc * 64 + nt * 32 + r32;
      f32x16 c = acc[mt][nt];
      if (mat < 2) {
        float ge = expf(gamma[col]);
        float sc = (mat == 0) ? ge * 0.08838834764831845f : ge;  // fold 1/sqrt(128) into Q
        int i2 = col >> 1;
#pragma unroll
        for (int rg = 0; rg < 16; ++rg) {
          int row = row0 + wr * 64 + mt * 32 + (rg & 3) + 8 * (rg >> 2) + 4 * h;
          int pos = row & 4095;
          float cv = cosT[pos * 64 + i2], sv = sinT[pos * 64 + i2];
          float val = c[rg];
          float ot = __shfl_xor(val, 1);
          // even d: t1*cos - t2*sin ; odd d: t1*sin + t2*cos
          float rr = (lane & 1) ? fmaf(val, cv, ot * sv) : fmaf(val, cv, -ot * sv);
          float v = rr * sc;
          if (mat == 0) {
            Qh[(size_t)row * 128 + col] = (_Float16)v;
          } else {
            size_t ka = (size_t)(row >> 5) * 4096 + (col >> 4) * 512 +
                        ((col >> 3) & 1) * 256 + (row & 31) * 8 + (col & 7);
            Kh[ka] = (_Float16)v;
          }
        }
      } else {
        // V fragment-major: rg group g covers 4 consecutive kv at fixed d=col.
#pragma unroll
        for (int g = 0; g < 4; ++g) {
          union { _Float16 hh[4]; uint2 u; } pk;
#pragma unroll
          for (int j2 = 0; j2 < 4; ++j2) pk.hh[j2] = (_Float16)c[g * 4 + j2];
          int kv = row0 + wr * 64 + mt * 32 + 8 * g + 4 * h;  // multiple of 4
          size_t va = (size_t)(kv >> 5) * 4096 +
                      ((col >> 5) * 2 + ((kv >> 4) & 1)) * 512 +
                      ((kv >> 3) & 1) * 256 + (col & 31) * 8 + (kv & 7);
          *(uint2*)(VT + va) = pk.u;
        }
      }
    }
}

// ---------------- kernel 2: flash attention (no-LDS loop, 16 waves) --------
// grid = B*64 blocks, 1024 threads = 16 waves: s = kv stream (0..7), wq = q tile (0/1)
// 4 waves/SIMD for TLP; K/V fragment-major direct loads; shfl_xor cross-half
// exchanges (proven form); LDS only in the merge epilogue.
__global__ __launch_bounds__(1024) void k_attn(
    const _Float16* __restrict__ Qh, const _Float16* __restrict__ Kh,
    const _Float16* __restrict__ VT, float* __restrict__ out) {
  extern __shared__ __align__(16) unsigned char lds_raw[];
  const int tid = threadIdx.x;
  const int bid = blockIdx.x;
  const int xcd = bid & 7;
  const int b  = xcd >> 1;
  const int q0 = ((xcd & 1) + 2 * (bid >> 3)) * 64;
  const int wid = tid >> 6, lane = tid & 63;
  const int s = wid >> 1, wq = wid & 1;
  const int r32 = lane & 31, h = lane >> 5;

  // Q fragments in registers (B-operand of swapped QK^T)
  const _Float16* qrow = Qh + (size_t)(b * 4096 + q0 + wq * 32 + r32) * 128;
  h8 qf[8];
#pragma unroll
  for (int kk = 0; kk < 8; ++kk) qf[kk] = *(const h8*)(qrow + kk * 16 + h * 8);

  // fragment bases for this wave's stream (tiles t = b*128 + 8*i + s)
  const size_t TSTRIDE = 8 * 4096;   // halves per iteration step (8 tiles)
  const _Float16* Kfb = Kh + (size_t)(b * 128 + s) * 4096 + lane * 8;
  const _Float16* Vfb = VT + (size_t)(b * 128 + s) * 4096 + lane * 8;

  f32x16 o_acc[4];
#pragma unroll
  for (int dt = 0; dt < 4; ++dt)
#pragma unroll
    for (int r = 0; r < 16; ++r) o_acc[dt][r] = 0.f;
  float mcur = -INFINITY, lsum = 0.f;

  // preload K fragments for iter 0
  h8 kf[8];
#pragma unroll
  for (int kk = 0; kk < 8; ++kk) kf[kk] = *(const h8*)(Kfb + kk * 512);

  for (int i = 0; i < 16; ++i) {
    // V fragments for this tile (consumed by PV ~ end of iteration)
    const _Float16* Vcur = Vfb + (size_t)i * TSTRIDE;
    h8 vf[8];
#pragma unroll
    for (int u = 0; u < 8; ++u) vf[u] = *(const h8*)(Vcur + u * 512);

    // QK^T consuming kf; roll-refill kf for next tile of this stream
    const _Float16* Kn = Kfb + (size_t)(i + 1) * TSTRIDE;
    f32x16 st0, st1;
#pragma unroll
    for (int r = 0; r < 16; ++r) { st0[r] = 0.f; st1[r] = 0.f; }
    __builtin_amdgcn_s_setprio(1);
#pragma unroll
    for (int kk = 0; kk < 8; ++kk) {
      h8 a = kf[kk];
      if (i < 15) kf[kk] = *(const h8*)(Kn + kk * 512);
      if (kk & 1) st1 = __builtin_amdgcn_mfma_f32_32x32x16_f16(a, qf[kk], st1, 0, 0, 0);
      else        st0 = __builtin_amdgcn_mfma_f32_32x32x16_f16(a, qf[kk], st0, 0, 0, 0);
    }
    __builtin_amdgcn_s_setprio(0);
    f32x16 st = st0 + st1;

    // online softmax (per lane = one q row; partner half in lane^32)
    float pm = fmaxf(fmaxf(fmaxf(st[0], st[1]), fmaxf(st[2], st[3])),
                     fmaxf(fmaxf(st[4], st[5]), fmaxf(st[6], st[7])));
    float pm2 = fmaxf(fmaxf(fmaxf(st[8], st[9]), fmaxf(st[10], st[11])),
                      fmaxf(fmaxf(st[12], st[13]), fmaxf(st[14], st[15])));
    pm = fmaxf(pm, pm2);
    pm = fmaxf(pm, __shfl_xor(pm, 32));
    // defer-max: only rescale when the running max grew by > 8
    if (!__all(pm - mcur <= 8.0f)) {
      float mnew = fmaxf(mcur, pm);
      float fsc = exp2f((mcur - mnew) * L2E);
      lsum *= fsc;
#pragma unroll
      for (int dt = 0; dt < 4; ++dt) o_acc[dt] = o_acc[dt] * fsc;
      mcur = mnew;
    }
    float mn2 = mcur * L2E;
    float pv[16]; float ps = 0.f;
#pragma unroll
    for (int r = 0; r < 16; ++r) { pv[r] = exp2f(fmaf(st[r], L2E, -mn2)); ps += pv[r]; }
    ps += __shfl_xor(ps, 32);
    lsum += ps;

    // pack P to half2 words; kv pair of word t (own half h): 8*(t>>1) + 4h + 2*(t&1)
    unsigned int wrd[8], owd[8];
#pragma unroll
    for (int t8 = 0; t8 < 8; ++t8) {
      auto hp = __builtin_amdgcn_cvt_pkrtz(pv[2 * t8], pv[2 * t8 + 1]);
      wrd[t8] = __builtin_bit_cast(unsigned int, hp);
    }
#pragma unroll
    for (int t8 = 0; t8 < 8; ++t8) owd[t8] = (unsigned int)__shfl_xor((int)wrd[t8], 32);
    const bool hb = (h != 0);
    __builtin_amdgcn_s_setprio(1);
#pragma unroll
    for (int kvb = 0; kvb < 2; ++kvb) {
      union { unsigned int u[4]; h8 v; } pb;
      pb.u[0] = hb ? owd[4 * kvb + 2] : wrd[4 * kvb + 0];
      pb.u[1] = hb ? owd[4 * kvb + 3] : wrd[4 * kvb + 1];
      pb.u[2] = hb ? wrd[4 * kvb + 2] : owd[4 * kvb + 0];
      pb.u[3] = hb ? wrd[4 * kvb + 3] : owd[4 * kvb + 1];
#pragma unroll
      for (int dt = 0; dt < 4; ++dt)
        o_acc[dt] = __builtin_amdgcn_mfma_f32_32x32x16_f16(vf[dt * 2 + kvb], pb.v, o_acc[dt], 0, 0, 0);
    }
    __builtin_amdgcn_s_setprio(0);
  }

  // ---- epilogue: merge 8 kv streams ----
  // (a) exchange m,l; every wave pre-rescales its own o_acc
  float* ML = (float*)lds_raw;                 // [16 wid][m 32 | l 32] = 4 KB
  if (lane < 32) {
    ML[wid * 64 + lane] = mcur;
    ML[wid * 64 + 32 + lane] = lsum;
  }
  __syncthreads();
  float mstar = -INFINITY;
  float msv[8], lsv[8];
#pragma unroll
  for (int s2 = 0; s2 < 8; ++s2) {
    msv[s2] = ML[(s2 * 2 + wq) * 64 + r32];
    lsv[s2] = ML[(s2 * 2 + wq) * 64 + 32 + r32];
    mstar = fmaxf(mstar, msv[s2]);
  }
  float L = 0.f;
#pragma unroll
  for (int s2 = 0; s2 < 8; ++s2) L += lsv[s2] * exp2f((msv[s2] - mstar) * L2E);
  float fown = exp2f((msv[s] - mstar) * L2E);
  float inv = 1.0f / L;
#pragma unroll
  for (int dt = 0; dt < 4; ++dt) o_acc[dt] = o_acc[dt] * fown;
  __syncthreads();

  // (b) log2 sum rounds through LDS: 4 slots x [2 wq][64 rows][64 lanes] = 128 KB
  float* MB = (float*)lds_raw;
  auto mbw = [&](int slot) {
    float* p = MB + (size_t)((slot * 2 + wq) * 64) * 64;
#pragma unroll
    for (int dt = 0; dt < 4; ++dt)
#pragma unroll
      for (int rg = 0; rg < 16; ++rg) p[(dt * 16 + rg) * 64 + lane] = o_acc[dt][rg];
  };
  auto mba = [&](int slot) {
    float* p = MB + (size_t)((slot * 2 + wq) * 64) * 64;
#pragma unroll
    for (int dt = 0; dt < 4; ++dt)
#pragma unroll
      for (int rg = 0; rg < 16; ++rg) o_acc[dt][rg] += p[(dt * 16 + rg) * 64 + lane];
  };
  if (s >= 4) mbw(s - 4);
  __syncthreads();
  if (s < 4) mba(s);
  __syncthreads();
  if (s == 2 || s == 3) mbw(s - 2);
  __syncthreads();
  if (s < 2) mba(s);
  __syncthreads();
  if (s == 1) mbw(0);
  __syncthreads();
  if (s == 0) {
    mba(0);
#pragma unroll
    for (int dt = 0; dt < 4; ++dt) o_acc[dt] = o_acc[dt] * inv;
  }
  __syncthreads();
  // (c) transpose via LDS and store
  float* OT = (float*)lds_raw;                 // [64 q][129]
  if (s == 0) {
#pragma unroll
    for (int dt = 0; dt < 4; ++dt)
#pragma unroll
      for (int rg = 0; rg < 16; ++rg) {
        int d = dt * 32 + (rg & 3) + 8 * (rg >> 2) + 4 * h;
        OT[(wq * 32 + r32) * 129 + d] = o_acc[dt][rg];
      }
  }
  __syncthreads();
#pragma unroll
  for (int pi = 0; pi < 8; ++pi) {
    int idx = pi * 1024 + tid;
    int qr = idx >> 7, c = idx & 127;
    out[(size_t)(b * 4096 + q0 + qr) * 128 + c] = OT[qr * 129 + c];
  }
}

// ---------------- launcher ----------------
extern "C" void kernel_launch(void* const* d_in, const int* in_sizes, int n_in,
                              void* d_out, int out_size, void* d_ws, size_t ws_size,
                              hipStream_t stream) {
  const float* x     = (const float*)d_in[0];
  const float* cosT  = (const float*)d_in[1];
  const float* sinT  = (const float*)d_in[2];
  const float* Wq    = (const float*)d_in[3];
  const float* Wk    = (const float*)d_in[4];
  const float* Wv    = (const float*)d_in[5];
  const float* gamma = (const float*)d_in[6];
  char* ws = (char*)d_ws;
  _Float16* xh = (_Float16*)(ws);                    // 33,554,432 B
  _Float16* WT = (_Float16*)(ws + 33554432);         //    786,432 B
  _Float16* Qh = (_Float16*)(ws + 34340864);         //  4,194,304 B
  _Float16* Kh = (_Float16*)(ws + 38535168);         //  4,194,304 B (fragment-major)
  _Float16* VT = (_Float16*)(ws + 42729472);         //  4,194,304 B (fragment-major)
  float* out = (float*)d_out;

  (void)hipFuncSetAttribute(reinterpret_cast<const void*>(k_attn),
                            hipFuncAttributeMaxDynamicSharedMemorySize, 131072);

  hipLaunchKernelGGL(k_cvt_x, dim3(8192), dim3(256), 0, stream, x, xh);
  hipLaunchKernelGGL(k_cvt_w, dim3(1536), dim3(256), 0, stream, Wq, Wk, Wv, WT);
  hipLaunchKernelGGL(k_proj, dim3(384), dim3(256), 0, stream, xh, WT, cosT, sinT, gamma, Qh, Kh, VT);
  hipLaunchKernelGGL(k_attn, dim3(256), dim3(1024), 131072, stream, Qh, Kh, VT, out);
}

// Round 9
// 178.351 us; speedup vs baseline: 2.3078x; 2.3078x over previous
//
#include <hip/hip_runtime.h>

typedef _Float16 h8  __attribute__((ext_vector_type(8)));
typedef float f32x16 __attribute__((ext_vector_type(16)));

#define L2E 1.4426950408889634f

__device__ __forceinline__ void gll16(const void* g, void* l) {
  __builtin_amdgcn_global_load_lds((const __attribute__((address_space(1))) void*)g,
                                   (__attribute__((address_space(3))) void*)l, 16, 0, 0);
}

// ---------------- kernel 0: x (f32) -> xh (f16) ----------------
__global__ void k_cvt_x(const float* __restrict__ x, _Float16* __restrict__ xh) {
  int i = (blockIdx.x * 256 + threadIdx.x) * 8;
  float4 a = *(const float4*)(x + i);
  float4 b = *(const float4*)(x + i + 4);
  h8 o;
  o[0] = (_Float16)a.x; o[1] = (_Float16)a.y; o[2] = (_Float16)a.z; o[3] = (_Float16)a.w;
  o[4] = (_Float16)b.x; o[5] = (_Float16)b.y; o[6] = (_Float16)b.z; o[7] = (_Float16)b.w;
  *(h8*)(xh + i) = o;
}

// ---------------- kernel 0b: W (1024x128 f32) -> WT (3x128x1024 f16) ------
__global__ void k_cvt_w(const float* __restrict__ Wq, const float* __restrict__ Wk,
                        const float* __restrict__ Wv, _Float16* __restrict__ WT) {
  int id = blockIdx.x * 256 + threadIdx.x;     // 0 .. 3*131072-1
  int mat = id >> 17;
  int rem = id & 131071;
  int k = rem >> 7;
  int c = rem & 127;
  const float* W = (mat == 0) ? Wq : ((mat == 1) ? Wk : Wv);
  WT[mat * 131072 + c * 1024 + k] = (_Float16)W[rem];
}

// ---------------- kernel 1: QKV projection + rotary + gate ----------------
// grid = 128 row-tiles * 3 matrices; 256 threads (4 waves of 2x2 over 128x128)
// Q: row-major [16384][128].
// K: fragment-major for mfma_32x32x16 A-operand:
//    half-index = (kv>>5)*4096 + (d>>4)*512 + ((d>>3)&1)*256 + (kv&31)*8 + (d&7)
// V: fragment-major (A-operand of PV, rows = d, k-dim = kv):
//    half-index = (kv>>5)*4096 + ((d>>5)*2 + ((kv>>4)&1))*512 + ((kv>>3)&1)*256 + (d&31)*8 + (kv&7)
__global__ __launch_bounds__(256, 2) void k_proj(
    const _Float16* __restrict__ xh,   // [16384][1024]
    const _Float16* __restrict__ WT,   // [3][128][1024]
    const float* __restrict__ cosT, const float* __restrict__ sinT,  // [4096][64]
    const float* __restrict__ gamma,
    _Float16* __restrict__ Qh, _Float16* __restrict__ Kh, _Float16* __restrict__ VT) {
  __shared__ __align__(16) unsigned char lds[65536];  // [2 phase][x 16KB | w 16KB]
  const int tid = threadIdx.x;
  const int rt  = blockIdx.x & 127;
  const int mat = blockIdx.x >> 7;
  const int w = tid >> 6, lane = tid & 63;
  const int wr = w >> 1, wc = w & 1;
  const int r32 = lane & 31, h = lane >> 5;
  const int row0 = rt * 128;
  const _Float16* Wbase = WT + mat * 131072;

  auto stage = [&](int j) {
    int k0 = j * 64;
    unsigned char* xb = lds + (j & 1) * 32768;
    unsigned char* wb = xb + 16384;
#pragma unroll
    for (int ii = 0; ii < 4; ++ii) {
      int off = ii * 4096 + tid * 16;
      int r = off >> 7;            // row in tile (128B rows)
      int c = (off >> 4) & 7;      // 16B chunk slot
      gll16(xh + (size_t)(row0 + r) * 1024 + k0 + ((c ^ (r & 7)) * 8), xb + off);
    }
#pragma unroll
    for (int ii = 0; ii < 4; ++ii) {
      int off = ii * 4096 + tid * 16;
      int r = off >> 7;
      int c = (off >> 4) & 7;
      gll16(Wbase + (size_t)r * 1024 + k0 + ((c ^ (r & 7)) * 8), wb + off);
    }
  };

  f32x16 acc[2][2];
#pragma unroll
  for (int a_ = 0; a_ < 2; ++a_)
#pragma unroll
    for (int b_ = 0; b_ < 2; ++b_)
#pragma unroll
      for (int r = 0; r < 16; ++r) acc[a_][b_][r] = 0.f;

  stage(0);
  for (int j = 0; j < 16; ++j) {
    if (j < 15) {
      stage(j + 1);
      asm volatile("s_waitcnt vmcnt(8)\n\ts_barrier" ::: "memory");
    } else {
      asm volatile("s_waitcnt vmcnt(0)\n\ts_barrier" ::: "memory");
    }
    const _Float16* xt = (const _Float16*)(lds + (j & 1) * 32768);
    const _Float16* wt = xt + 8192;
#pragma unroll
    for (int kk = 0; kk < 4; ++kk) {
      h8 a0, a1, b0, b1;
      { int r = wr * 64 + r32;      a0 = *(const h8*)(xt + r * 64 + (((kk * 2 + h) ^ (r & 7)) * 8)); }
      { int r = wr * 64 + 32 + r32; a1 = *(const h8*)(xt + r * 64 + (((kk * 2 + h) ^ (r & 7)) * 8)); }
      { int r = wc * 64 + r32;      b0 = *(const h8*)(wt + r * 64 + (((kk * 2 + h) ^ (r & 7)) * 8)); }
      { int r = wc * 64 + 32 + r32; b1 = *(const h8*)(wt + r * 64 + (((kk * 2 + h) ^ (r & 7)) * 8)); }
      acc[0][0] = __builtin_amdgcn_mfma_f32_32x32x16_f16(a0, b0, acc[0][0], 0, 0, 0);
      acc[0][1] = __builtin_amdgcn_mfma_f32_32x32x16_f16(a0, b1, acc[0][1], 0, 0, 0);
      acc[1][0] = __builtin_amdgcn_mfma_f32_32x32x16_f16(a1, b0, acc[1][0], 0, 0, 0);
      acc[1][1] = __builtin_amdgcn_mfma_f32_32x32x16_f16(a1, b1, acc[1][1], 0, 0, 0);
    }
    asm volatile("s_waitcnt lgkmcnt(0)\n\ts_barrier" ::: "memory");
  }

#pragma unroll
  for (int mt = 0; mt < 2; ++mt)
#pragma unroll
    for (int nt = 0; nt < 2; ++nt) {
      int col = wc * 64 + nt * 32 + r32;
      f32x16 c = acc[mt][nt];
      if (mat < 2) {
        float ge = expf(gamma[col]);
        float sc = (mat == 0) ? ge * 0.08838834764831845f : ge;  // fold 1/sqrt(128) into Q
        int i2 = col >> 1;
#pragma unroll
        for (int rg = 0; rg < 16; ++rg) {
          int row = row0 + wr * 64 + mt * 32 + (rg & 3) + 8 * (rg >> 2) + 4 * h;
          int pos = row & 4095;
          float cv = cosT[pos * 64 + i2], sv = sinT[pos * 64 + i2];
          float val = c[rg];
          float ot = __shfl_xor(val, 1);
          // even d: t1*cos - t2*sin ; odd d: t1*sin + t2*cos
          float rr = (lane & 1) ? fmaf(val, cv, ot * sv) : fmaf(val, cv, -ot * sv);
          float v = rr * sc;
          if (mat == 0) {
            Qh[(size_t)row * 128 + col] = (_Float16)v;
          } else {
            size_t ka = (size_t)(row >> 5) * 4096 + (col >> 4) * 512 +
                        ((col >> 3) & 1) * 256 + (row & 31) * 8 + (col & 7);
            Kh[ka] = (_Float16)v;
          }
        }
      } else {
        // V fragment-major: rg group g covers 4 consecutive kv at fixed d=col.
#pragma unroll
        for (int g = 0; g < 4; ++g) {
          union { _Float16 hh[4]; uint2 u; } pk;
#pragma unroll
          for (int j2 = 0; j2 < 4; ++j2) pk.hh[j2] = (_Float16)c[g * 4 + j2];
          int kv = row0 + wr * 64 + mt * 32 + 8 * g + 4 * h;  // multiple of 4
          size_t va = (size_t)(kv >> 5) * 4096 +
                      ((col >> 5) * 2 + ((kv >> 4) & 1)) * 512 +
                      ((kv >> 3) & 1) * 256 + (col & 31) * 8 + (kv & 7);
          *(uint2*)(VT + va) = pk.u;
        }
      }
    }
}

// ---------------- kernel 2: flash attention (no-LDS loop) ------------------
// grid = 512 blocks x 512 threads = 8 waves: s = kv stream (0..7), ONE 32-row
// q-tile per block. 66 KiB LDS -> 2 blocks/CU -> 4 waves/SIMD.
// K/V fragment-major direct loads; LDS only in the merge epilogue.
__global__ __launch_bounds__(512, 4) void k_attn(
    const _Float16* __restrict__ Qh, const _Float16* __restrict__ Kh,
    const _Float16* __restrict__ VT, float* __restrict__ out) {
  extern __shared__ __align__(16) unsigned char lds_raw[];
  const int tid = threadIdx.x;
  const int bid = blockIdx.x;
  const int xcd = bid & 7;
  const int b  = xcd >> 1;
  const int q0 = ((xcd & 1) + 2 * (bid >> 3)) * 32;
  const int s = tid >> 6, lane = tid & 63;
  const int r32 = lane & 31, h = lane >> 5;

  // Q fragments in registers (B-operand of swapped QK^T)
  const _Float16* qrow = Qh + (size_t)(b * 4096 + q0 + r32) * 128;
  h8 qf[8];
#pragma unroll
  for (int kk = 0; kk < 8; ++kk) qf[kk] = *(const h8*)(qrow + kk * 16 + h * 8);

  // fragment bases for this wave's stream (tiles t = b*128 + 8*i + s)
  const size_t TSTRIDE = 8 * 4096;   // halves per iteration step (8 tiles)
  const _Float16* Kfb = Kh + (size_t)(b * 128 + s) * 4096 + lane * 8;
  const _Float16* Vfb = VT + (size_t)(b * 128 + s) * 4096 + lane * 8;

  f32x16 o_acc[4];
#pragma unroll
  for (int dt = 0; dt < 4; ++dt)
#pragma unroll
    for (int r = 0; r < 16; ++r) o_acc[dt][r] = 0.f;
  float mcur = -INFINITY, lsum = 0.f;

  // preload K fragments for iter 0
  h8 kf[8];
#pragma unroll
  for (int kk = 0; kk < 8; ++kk) kf[kk] = *(const h8*)(Kfb + kk * 512);

  for (int i = 0; i < 16; ++i) {
    // QK^T consuming kf (single chained accumulator); roll-refill kf
    const _Float16* Kn = Kfb + (size_t)(i + 1) * TSTRIDE;
    f32x16 st;
#pragma unroll
    for (int r = 0; r < 16; ++r) st[r] = 0.f;
    __builtin_amdgcn_s_setprio(1);
#pragma unroll
    for (int kk = 0; kk < 8; ++kk) {
      h8 a = kf[kk];
      if (i < 15) kf[kk] = *(const h8*)(Kn + kk * 512);
      st = __builtin_amdgcn_mfma_f32_32x32x16_f16(a, qf[kk], st, 0, 0, 0);
    }
    __builtin_amdgcn_s_setprio(0);

    // online softmax (per lane = one q row; partner half in lane^32)
    float pm = fmaxf(fmaxf(fmaxf(st[0], st[1]), fmaxf(st[2], st[3])),
                     fmaxf(fmaxf(st[4], st[5]), fmaxf(st[6], st[7])));
    float pm2 = fmaxf(fmaxf(fmaxf(st[8], st[9]), fmaxf(st[10], st[11])),
                      fmaxf(fmaxf(st[12], st[13]), fmaxf(st[14], st[15])));
    pm = fmaxf(pm, pm2);
    pm = fmaxf(pm, __shfl_xor(pm, 32));
    // defer-max: only rescale when the running max grew by > 8
    if (!__all(pm - mcur <= 8.0f)) {
      float mnew = fmaxf(mcur, pm);
      float fsc = exp2f((mcur - mnew) * L2E);
      lsum *= fsc;
#pragma unroll
      for (int dt = 0; dt < 4; ++dt) o_acc[dt] = o_acc[dt] * fsc;
      mcur = mnew;
    }
    float mn2 = mcur * L2E;
    float pv[16]; float ps = 0.f;
#pragma unroll
    for (int r = 0; r < 16; ++r) { pv[r] = exp2f(fmaf(st[r], L2E, -mn2)); ps += pv[r]; }
    ps += __shfl_xor(ps, 32);
    lsum += ps;

    // pack P to half2 words; kv pair of word t (own half h): 8*(t>>1) + 4h + 2*(t&1)
    unsigned int wrd[8], owd[8];
#pragma unroll
    for (int t8 = 0; t8 < 8; ++t8) {
      auto hp = __builtin_amdgcn_cvt_pkrtz(pv[2 * t8], pv[2 * t8 + 1]);
      wrd[t8] = __builtin_bit_cast(unsigned int, hp);
    }
#pragma unroll
    for (int t8 = 0; t8 < 8; ++t8) owd[t8] = (unsigned int)__shfl_xor((int)wrd[t8], 32);
    const bool hb = (h != 0);
    const _Float16* Vcur = Vfb + (size_t)i * TSTRIDE;
    __builtin_amdgcn_s_setprio(1);
#pragma unroll
    for (int kvb = 0; kvb < 2; ++kvb) {
      union { unsigned int u[4]; h8 v; } pb;
      pb.u[0] = hb ? owd[4 * kvb + 2] : wrd[4 * kvb + 0];
      pb.u[1] = hb ? owd[4 * kvb + 3] : wrd[4 * kvb + 1];
      pb.u[2] = hb ? wrd[4 * kvb + 2] : owd[4 * kvb + 0];
      pb.u[3] = hb ? wrd[4 * kvb + 3] : owd[4 * kvb + 1];
      // V fragments for this half loaded lazily (L1/L2-resident)
      h8 vfk[4];
#pragma unroll
      for (int dt = 0; dt < 4; ++dt) vfk[dt] = *(const h8*)(Vcur + (dt * 2 + kvb) * 512);
#pragma unroll
      for (int dt = 0; dt < 4; ++dt)
        o_acc[dt] = __builtin_amdgcn_mfma_f32_32x32x16_f16(vfk[dt], pb.v, o_acc[dt], 0, 0, 0);
    }
    __builtin_amdgcn_s_setprio(0);
  }

  // ---- epilogue: merge 8 kv streams ----
  // LDS map: MB = 4 slots x 16 KB at [0,65536); ML = [8 s][m 32 | l 32] at 65536.
  float* ML = (float*)(lds_raw + 65536);
  if (lane < 32) {
    ML[s * 64 + lane] = mcur;
    ML[s * 64 + 32 + lane] = lsum;
  }
  __syncthreads();
  float mstar = -INFINITY;
  float msv[8], lsv[8];
#pragma unroll
  for (int s2 = 0; s2 < 8; ++s2) {
    msv[s2] = ML[s2 * 64 + r32];
    lsv[s2] = ML[s2 * 64 + 32 + r32];
    mstar = fmaxf(mstar, msv[s2]);
  }
  float L = 0.f;
#pragma unroll
  for (int s2 = 0; s2 < 8; ++s2) L += lsv[s2] * exp2f((msv[s2] - mstar) * L2E);
  float fown = exp2f((msv[s] - mstar) * L2E);
  float inv = 1.0f / L;
#pragma unroll
  for (int dt = 0; dt < 4; ++dt) o_acc[dt] = o_acc[dt] * fown;

  float* MB = (float*)lds_raw;
  auto mbw = [&](int slot) {
    float* p = MB + (size_t)slot * 4096;
#pragma unroll
    for (int dt = 0; dt < 4; ++dt)
#pragma unroll
      for (int rg = 0; rg < 16; ++rg) p[(dt * 16 + rg) * 64 + lane] = o_acc[dt][rg];
  };
  auto mba = [&](int slot) {
    float* p = MB + (size_t)slot * 4096;
#pragma unroll
    for (int dt = 0; dt < 4; ++dt)
#pragma unroll
      for (int rg = 0; rg < 16; ++rg) o_acc[dt][rg] += p[(dt * 16 + rg) * 64 + lane];
  };
  if (s >= 4) mbw(s - 4);
  __syncthreads();
  if (s < 4) mba(s);
  __syncthreads();
  if (s == 2 || s == 3) mbw(s - 2);
  __syncthreads();
  if (s < 2) mba(s);
  __syncthreads();
  if (s == 1) mbw(0);
  __syncthreads();
  if (s == 0) {
    mba(0);
#pragma unroll
    for (int dt = 0; dt < 4; ++dt) o_acc[dt] = o_acc[dt] * inv;
  }
  __syncthreads();
  // transpose via LDS and store: OT [32 q][129]
  float* OT = (float*)lds_raw;
  if (s == 0) {
#pragma unroll
    for (int dt = 0; dt < 4; ++dt)
#pragma unroll
      for (int rg = 0; rg < 16; ++rg) {
        int d = dt * 32 + (rg & 3) + 8 * (rg >> 2) + 4 * h;
        OT[r32 * 129 + d] = o_acc[dt][rg];
      }
  }
  __syncthreads();
#pragma unroll
  for (int pi = 0; pi < 8; ++pi) {
    int idx = pi * 512 + tid;
    int qr = idx >> 7, c = idx & 127;
    out[(size_t)(b * 4096 + q0 + qr) * 128 + c] = OT[qr * 129 + c];
  }
}

// ---------------- launcher ----------------
extern "C" void kernel_launch(void* const* d_in, const int* in_sizes, int n_in,
                              void* d_out, int out_size, void* d_ws, size_t ws_size,
                              hipStream_t stream) {
  const float* x     = (const float*)d_in[0];
  const float* cosT  = (const float*)d_in[1];
  const float* sinT  = (const float*)d_in[2];
  const float* Wq    = (const float*)d_in[3];
  const float* Wk    = (const float*)d_in[4];
  const float* Wv    = (const float*)d_in[5];
  const float* gamma = (const float*)d_in[6];
  char* ws = (char*)d_ws;
  _Float16* xh = (_Float16*)(ws);                    // 33,554,432 B
  _Float16* WT = (_Float16*)(ws + 33554432);         //    786,432 B
  _Float16* Qh = (_Float16*)(ws + 34340864);         //  4,194,304 B
  _Float16* Kh = (_Float16*)(ws + 38535168);         //  4,194,304 B (fragment-major)
  _Float16* VT = (_Float16*)(ws + 42729472);         //  4,194,304 B (fragment-major)
  float* out = (float*)d_out;

  (void)hipFuncSetAttribute(reinterpret_cast<const void*>(k_attn),
                            hipFuncAttributeMaxDynamicSharedMemorySize, 67584);

  hipLaunchKernelGGL(k_cvt_x, dim3(8192), dim3(256), 0, stream, x, xh);
  hipLaunchKernelGGL(k_cvt_w, dim3(1536), dim3(256), 0, stream, Wq, Wk, Wv, WT);
  hipLaunchKernelGGL(k_proj, dim3(384), dim3(256), 0, stream, xh, WT, cosT, sinT, gamma, Qh, Kh, VT);
  hipLaunchKernelGGL(k_attn, dim3(512), dim3(512), 67584, stream, Qh, Kh, VT, out);
}

// Round 10
// 143.755 us; speedup vs baseline: 2.8632x; 1.2407x over previous
//
#include <hip/hip_runtime.h>

typedef _Float16 h8  __attribute__((ext_vector_type(8)));
typedef float f32x16 __attribute__((ext_vector_type(16)));

#define L2E 1.4426950408889634f

__device__ __forceinline__ void gll16(const void* g, void* l) {
  __builtin_amdgcn_global_load_lds((const __attribute__((address_space(1))) void*)g,
                                   (__attribute__((address_space(3))) void*)l, 16, 0, 0);
}

// ---------------- kernel 0: x (f32) -> xh (f16) ----------------
__global__ void k_cvt_x(const float* __restrict__ x, _Float16* __restrict__ xh) {
  int i = (blockIdx.x * 256 + threadIdx.x) * 8;
  float4 a = *(const float4*)(x + i);
  float4 b = *(const float4*)(x + i + 4);
  h8 o;
  o[0] = (_Float16)a.x; o[1] = (_Float16)a.y; o[2] = (_Float16)a.z; o[3] = (_Float16)a.w;
  o[4] = (_Float16)b.x; o[5] = (_Float16)b.y; o[6] = (_Float16)b.z; o[7] = (_Float16)b.w;
  *(h8*)(xh + i) = o;
}

// ---------------- kernel 0b: W (1024x128 f32) -> WT (3x128x1024 f16) ------
__global__ void k_cvt_w(const float* __restrict__ Wq, const float* __restrict__ Wk,
                        const float* __restrict__ Wv, _Float16* __restrict__ WT) {
  int id = blockIdx.x * 256 + threadIdx.x;     // 0 .. 3*131072-1
  int mat = id >> 17;
  int rem = id & 131071;
  int k = rem >> 7;
  int c = rem & 127;
  const float* W = (mat == 0) ? Wq : ((mat == 1) ? Wk : Wv);
  WT[mat * 131072 + c * 1024 + k] = (_Float16)W[rem];
}

// ---------------- kernel 1: QKV projection + rotary + gate ----------------
// grid = 128 row-tiles * 3 matrices; 256 threads (4 waves of 2x2 over 128x128)
// Q: row-major [16384][128].
// K: fragment-major for mfma_32x32x16 A-operand:
//    half-index = (kv>>5)*4096 + (d>>4)*512 + ((d>>3)&1)*256 + (kv&31)*8 + (d&7)
// V: fragment-major (A-operand of PV, rows = d, k-dim = kv):
//    half-index = (kv>>5)*4096 + ((d>>5)*2 + ((kv>>4)&1))*512 + ((kv>>3)&1)*256 + (d&31)*8 + (kv&7)
__global__ __launch_bounds__(256, 2) void k_proj(
    const _Float16* __restrict__ xh,   // [16384][1024]
    const _Float16* __restrict__ WT,   // [3][128][1024]
    const float* __restrict__ cosT, const float* __restrict__ sinT,  // [4096][64]
    const float* __restrict__ gamma,
    _Float16* __restrict__ Qh, _Float16* __restrict__ Kh, _Float16* __restrict__ VT) {
  __shared__ __align__(16) unsigned char lds[65536];  // [2 phase][x 16KB | w 16KB]
  const int tid = threadIdx.x;
  const int rt  = blockIdx.x & 127;
  const int mat = blockIdx.x >> 7;
  const int w = tid >> 6, lane = tid & 63;
  const int wr = w >> 1, wc = w & 1;
  const int r32 = lane & 31, h = lane >> 5;
  const int row0 = rt * 128;
  const _Float16* Wbase = WT + mat * 131072;

  auto stage = [&](int j) {
    int k0 = j * 64;
    unsigned char* xb = lds + (j & 1) * 32768;
    unsigned char* wb = xb + 16384;
#pragma unroll
    for (int ii = 0; ii < 4; ++ii) {
      int off = ii * 4096 + tid * 16;
      int r = off >> 7;            // row in tile (128B rows)
      int c = (off >> 4) & 7;      // 16B chunk slot
      gll16(xh + (size_t)(row0 + r) * 1024 + k0 + ((c ^ (r & 7)) * 8), xb + off);
    }
#pragma unroll
    for (int ii = 0; ii < 4; ++ii) {
      int off = ii * 4096 + tid * 16;
      int r = off >> 7;
      int c = (off >> 4) & 7;
      gll16(Wbase + (size_t)r * 1024 + k0 + ((c ^ (r & 7)) * 8), wb + off);
    }
  };

  f32x16 acc[2][2];
#pragma unroll
  for (int a_ = 0; a_ < 2; ++a_)
#pragma unroll
    for (int b_ = 0; b_ < 2; ++b_)
#pragma unroll
      for (int r = 0; r < 16; ++r) acc[a_][b_][r] = 0.f;

  stage(0);
  for (int j = 0; j < 16; ++j) {
    if (j < 15) {
      stage(j + 1);
      asm volatile("s_waitcnt vmcnt(8)\n\ts_barrier" ::: "memory");
    } else {
      asm volatile("s_waitcnt vmcnt(0)\n\ts_barrier" ::: "memory");
    }
    const _Float16* xt = (const _Float16*)(lds + (j & 1) * 32768);
    const _Float16* wt = xt + 8192;
#pragma unroll
    for (int kk = 0; kk < 4; ++kk) {
      h8 a0, a1, b0, b1;
      { int r = wr * 64 + r32;      a0 = *(const h8*)(xt + r * 64 + (((kk * 2 + h) ^ (r & 7)) * 8)); }
      { int r = wr * 64 + 32 + r32; a1 = *(const h8*)(xt + r * 64 + (((kk * 2 + h) ^ (r & 7)) * 8)); }
      { int r = wc * 64 + r32;      b0 = *(const h8*)(wt + r * 64 + (((kk * 2 + h) ^ (r & 7)) * 8)); }
      { int r = wc * 64 + 32 + r32; b1 = *(const h8*)(wt + r * 64 + (((kk * 2 + h) ^ (r & 7)) * 8)); }
      acc[0][0] = __builtin_amdgcn_mfma_f32_32x32x16_f16(a0, b0, acc[0][0], 0, 0, 0);
      acc[0][1] = __builtin_amdgcn_mfma_f32_32x32x16_f16(a0, b1, acc[0][1], 0, 0, 0);
      acc[1][0] = __builtin_amdgcn_mfma_f32_32x32x16_f16(a1, b0, acc[1][0], 0, 0, 0);
      acc[1][1] = __builtin_amdgcn_mfma_f32_32x32x16_f16(a1, b1, acc[1][1], 0, 0, 0);
    }
    asm volatile("s_waitcnt lgkmcnt(0)\n\ts_barrier" ::: "memory");
  }

#pragma unroll
  for (int mt = 0; mt < 2; ++mt)
#pragma unroll
    for (int nt = 0; nt < 2; ++nt) {
      int col = wc * 64 + nt * 32 + r32;
      f32x16 c = acc[mt][nt];
      if (mat < 2) {
        float ge = expf(gamma[col]);
        float sc = (mat == 0) ? ge * 0.08838834764831845f : ge;  // fold 1/sqrt(128) into Q
        int i2 = col >> 1;
#pragma unroll
        for (int rg = 0; rg < 16; ++rg) {
          int row = row0 + wr * 64 + mt * 32 + (rg & 3) + 8 * (rg >> 2) + 4 * h;
          int pos = row & 4095;
          float cv = cosT[pos * 64 + i2], sv = sinT[pos * 64 + i2];
          float val = c[rg];
          float ot = __shfl_xor(val, 1);
          // even d: t1*cos - t2*sin ; odd d: t1*sin + t2*cos
          float rr = (lane & 1) ? fmaf(val, cv, ot * sv) : fmaf(val, cv, -ot * sv);
          float v = rr * sc;
          if (mat == 0) {
            Qh[(size_t)row * 128 + col] = (_Float16)v;
          } else {
            size_t ka = (size_t)(row >> 5) * 4096 + (col >> 4) * 512 +
                        ((col >> 3) & 1) * 256 + (row & 31) * 8 + (col & 7);
            Kh[ka] = (_Float16)v;
          }
        }
      } else {
        // V fragment-major: rg group g covers 4 consecutive kv at fixed d=col.
#pragma unroll
        for (int g = 0; g < 4; ++g) {
          union { _Float16 hh[4]; uint2 u; } pk;
#pragma unroll
          for (int j2 = 0; j2 < 4; ++j2) pk.hh[j2] = (_Float16)c[g * 4 + j2];
          int kv = row0 + wr * 64 + mt * 32 + 8 * g + 4 * h;  // multiple of 4
          size_t va = (size_t)(kv >> 5) * 4096 +
                      ((col >> 5) * 2 + ((kv >> 4) & 1)) * 512 +
                      ((kv >> 3) & 1) * 256 + (col & 31) * 8 + (kv & 7);
          *(uint2*)(VT + va) = pk.u;
        }
      }
    }
}

// ---------------- kernel 2: flash attention (no-LDS loop) ------------------
// grid = 512 blocks x 512 threads = 8 waves: s = kv stream (0..7), ONE 32-row
// q-tile per block. 66 KiB LDS + VGPR<=128 -> 2 blocks/CU -> 4 waves/SIMD
// from hardware occupancy (launch_bounds kept at (512,2): the (512,4) hint
// made the allocator shrink to 64 VGPR and spill 220MB to scratch).
__global__ __launch_bounds__(512, 2) void k_attn(
    const _Float16* __restrict__ Qh, const _Float16* __restrict__ Kh,
    const _Float16* __restrict__ VT, float* __restrict__ out) {
  extern __shared__ __align__(16) unsigned char lds_raw[];
  const int tid = threadIdx.x;
  const int bid = blockIdx.x;
  const int xcd = bid & 7;
  const int b  = xcd >> 1;
  const int q0 = ((xcd & 1) + 2 * (bid >> 3)) * 32;
  const int s = tid >> 6, lane = tid & 63;
  const int r32 = lane & 31, h = lane >> 5;

  // Q fragments in registers (B-operand of swapped QK^T)
  const _Float16* qrow = Qh + (size_t)(b * 4096 + q0 + r32) * 128;
  h8 qf[8];
#pragma unroll
  for (int kk = 0; kk < 8; ++kk) qf[kk] = *(const h8*)(qrow + kk * 16 + h * 8);

  // fragment bases for this wave's stream (tiles t = b*128 + 8*i + s)
  const size_t TSTRIDE = 8 * 4096;   // halves per iteration step (8 tiles)
  const _Float16* Kfb = Kh + (size_t)(b * 128 + s) * 4096 + lane * 8;
  const _Float16* Vfb = VT + (size_t)(b * 128 + s) * 4096 + lane * 8;

  f32x16 o_acc[4];
#pragma unroll
  for (int dt = 0; dt < 4; ++dt)
#pragma unroll
    for (int r = 0; r < 16; ++r) o_acc[dt][r] = 0.f;
  float mcur = -INFINITY, lsum = 0.f;

  // preload K fragments for iter 0
  h8 kf[8];
#pragma unroll
  for (int kk = 0; kk < 8; ++kk) kf[kk] = *(const h8*)(Kfb + kk * 512);

  for (int i = 0; i < 16; ++i) {
    // QK^T consuming kf (single chained accumulator); roll-refill kf
    const _Float16* Kn = Kfb + (size_t)(i + 1) * TSTRIDE;
    f32x16 st;
#pragma unroll
    for (int r = 0; r < 16; ++r) st[r] = 0.f;
    __builtin_amdgcn_s_setprio(1);
#pragma unroll
    for (int kk = 0; kk < 8; ++kk) {
      h8 a = kf[kk];
      if (i < 15) kf[kk] = *(const h8*)(Kn + kk * 512);
      st = __builtin_amdgcn_mfma_f32_32x32x16_f16(a, qf[kk], st, 0, 0, 0);
    }
    __builtin_amdgcn_s_setprio(0);

    // online softmax (per lane = one q row; partner half in lane^32)
    float pm = fmaxf(fmaxf(fmaxf(st[0], st[1]), fmaxf(st[2], st[3])),
                     fmaxf(fmaxf(st[4], st[5]), fmaxf(st[6], st[7])));
    float pm2 = fmaxf(fmaxf(fmaxf(st[8], st[9]), fmaxf(st[10], st[11])),
                      fmaxf(fmaxf(st[12], st[13]), fmaxf(st[14], st[15])));
    pm = fmaxf(pm, pm2);
    pm = fmaxf(pm, __shfl_xor(pm, 32));
    // defer-max: only rescale when the running max grew by > 8
    if (!__all(pm - mcur <= 8.0f)) {
      float mnew = fmaxf(mcur, pm);
      float fsc = exp2f((mcur - mnew) * L2E);
      lsum *= fsc;
#pragma unroll
      for (int dt = 0; dt < 4; ++dt) o_acc[dt] = o_acc[dt] * fsc;
      mcur = mnew;
    }
    float mn2 = mcur * L2E;
    float pv[16]; float ps = 0.f;
#pragma unroll
    for (int r = 0; r < 16; ++r) { pv[r] = exp2f(fmaf(st[r], L2E, -mn2)); ps += pv[r]; }
    ps += __shfl_xor(ps, 32);
    lsum += ps;

    // pack P to half2 words; kv pair of word t (own half h): 8*(t>>1) + 4h + 2*(t&1)
    unsigned int wrd[8], owd[8];
#pragma unroll
    for (int t8 = 0; t8 < 8; ++t8) {
      auto hp = __builtin_amdgcn_cvt_pkrtz(pv[2 * t8], pv[2 * t8 + 1]);
      wrd[t8] = __builtin_bit_cast(unsigned int, hp);
    }
#pragma unroll
    for (int t8 = 0; t8 < 8; ++t8) owd[t8] = (unsigned int)__shfl_xor((int)wrd[t8], 32);
    const bool hb = (h != 0);
    const _Float16* Vcur = Vfb + (size_t)i * TSTRIDE;
    __builtin_amdgcn_s_setprio(1);
#pragma unroll
    for (int kvb = 0; kvb < 2; ++kvb) {
      union { unsigned int u[4]; h8 v; } pb;
      pb.u[0] = hb ? owd[4 * kvb + 2] : wrd[4 * kvb + 0];
      pb.u[1] = hb ? owd[4 * kvb + 3] : wrd[4 * kvb + 1];
      pb.u[2] = hb ? wrd[4 * kvb + 2] : owd[4 * kvb + 0];
      pb.u[3] = hb ? wrd[4 * kvb + 3] : owd[4 * kvb + 1];
      // V fragments for this half loaded lazily (L1/L2-resident)
      h8 vfk[4];
#pragma unroll
      for (int dt = 0; dt < 4; ++dt) vfk[dt] = *(const h8*)(Vcur + (dt * 2 + kvb) * 512);
#pragma unroll
      for (int dt = 0; dt < 4; ++dt)
        o_acc[dt] = __builtin_amdgcn_mfma_f32_32x32x16_f16(vfk[dt], pb.v, o_acc[dt], 0, 0, 0);
    }
    __builtin_amdgcn_s_setprio(0);
  }

  // ---- epilogue: merge 8 kv streams ----
  // LDS map: MB = 4 slots x 16 KB at [0,65536); ML = [8 s][m 32 | l 32] at 65536.
  float* ML = (float*)(lds_raw + 65536);
  if (lane < 32) {
    ML[s * 64 + lane] = mcur;
    ML[s * 64 + 32 + lane] = lsum;
  }
  __syncthreads();
  float mstar = -INFINITY;
  float msv[8], lsv[8];
#pragma unroll
  for (int s2 = 0; s2 < 8; ++s2) {
    msv[s2] = ML[s2 * 64 + r32];
    lsv[s2] = ML[s2 * 64 + 32 + r32];
    mstar = fmaxf(mstar, msv[s2]);
  }
  float L = 0.f;
#pragma unroll
  for (int s2 = 0; s2 < 8; ++s2) L += lsv[s2] * exp2f((msv[s2] - mstar) * L2E);
  float fown = exp2f((msv[s] - mstar) * L2E);
  float inv = 1.0f / L;
#pragma unroll
  for (int dt = 0; dt < 4; ++dt) o_acc[dt] = o_acc[dt] * fown;

  float* MB = (float*)lds_raw;
  auto mbw = [&](int slot) {
    float* p = MB + (size_t)slot * 4096;
#pragma unroll
    for (int dt = 0; dt < 4; ++dt)
#pragma unroll
      for (int rg = 0; rg < 16; ++rg) p[(dt * 16 + rg) * 64 + lane] = o_acc[dt][rg];
  };
  auto mba = [&](int slot) {
    float* p = MB + (size_t)slot * 4096;
#pragma unroll
    for (int dt = 0; dt < 4; ++dt)
#pragma unroll
      for (int rg = 0; rg < 16; ++rg) o_acc[dt][rg] += p[(dt * 16 + rg) * 64 + lane];
  };
  if (s >= 4) mbw(s - 4);
  __syncthreads();
  if (s < 4) mba(s);
  __syncthreads();
  if (s == 2 || s == 3) mbw(s - 2);
  __syncthreads();
  if (s < 2) mba(s);
  __syncthreads();
  if (s == 1) mbw(0);
  __syncthreads();
  if (s == 0) {
    mba(0);
#pragma unroll
    for (int dt = 0; dt < 4; ++dt) o_acc[dt] = o_acc[dt] * inv;
  }
  __syncthreads();
  // transpose via LDS and store: OT [32 q][129]
  float* OT = (float*)lds_raw;
  if (s == 0) {
#pragma unroll
    for (int dt = 0; dt < 4; ++dt)
#pragma unroll
      for (int rg = 0; rg < 16; ++rg) {
        int d = dt * 32 + (rg & 3) + 8 * (rg >> 2) + 4 * h;
        OT[r32 * 129 + d] = o_acc[dt][rg];
      }
  }
  __syncthreads();
#pragma unroll
  for (int pi = 0; pi < 8; ++pi) {
    int idx = pi * 512 + tid;
    int qr = idx >> 7, c = idx & 127;
    out[(size_t)(b * 4096 + q0 + qr) * 128 + c] = OT[qr * 129 + c];
  }
}

// ---------------- launcher ----------------
extern "C" void kernel_launch(void* const* d_in, const int* in_sizes, int n_in,
                              void* d_out, int out_size, void* d_ws, size_t ws_size,
                              hipStream_t stream) {
  const float* x     = (const float*)d_in[0];
  const float* cosT  = (const float*)d_in[1];
  const float* sinT  = (const float*)d_in[2];
  const float* Wq    = (const float*)d_in[3];
  const float* Wk    = (const float*)d_in[4];
  const float* Wv    = (const float*)d_in[5];
  const float* gamma = (const float*)d_in[6];
  char* ws = (char*)d_ws;
  _Float16* xh = (_Float16*)(ws);                    // 33,554,432 B
  _Float16* WT = (_Float16*)(ws + 33554432);         //    786,432 B
  _Float16* Qh = (_Float16*)(ws + 34340864);         //  4,194,304 B
  _Float16* Kh = (_Float16*)(ws + 38535168);         //  4,194,304 B (fragment-major)
  _Float16* VT = (_Float16*)(ws + 42729472);         //  4,194,304 B (fragment-major)
  float* out = (float*)d_out;

  (void)hipFuncSetAttribute(reinterpret_cast<const void*>(k_attn),
                            hipFuncAttributeMaxDynamicSharedMemorySize, 67584);

  hipLaunchKernelGGL(k_cvt_x, dim3(8192), dim3(256), 0, stream, x, xh);
  hipLaunchKernelGGL(k_cvt_w, dim3(1536), dim3(256), 0, stream, Wq, Wk, Wv, WT);
  hipLaunchKernelGGL(k_proj, dim3(384), dim3(256), 0, stream, xh, WT, cosT, sinT, gamma, Qh, Kh, VT);
  hipLaunchKernelGGL(k_attn, dim3(512), dim3(512), 67584, stream, Qh, Kh, VT, out);
}